// Round 3
// baseline (282.172 us; speedup 1.0000x reference)
//
#include <hip/hip_runtime.h>
#include <hip/hip_bf16.h>
#include <math.h>

// Problem constants
#define Bn   2
#define Nn   2048
#define Kn   48
#define Cn   128
#define G2   16     // nodes per block in the tail kernel

typedef short bf16x8 __attribute__((ext_vector_type(8)));
typedef float f32x4  __attribute__((ext_vector_type(4)));

#if __has_builtin(__builtin_amdgcn_cvt_pk_bf16_f32)
#define HAS_PK 1
#endif

__device__ __forceinline__ short f2bf(float f) {
  union { float f; unsigned u; } v; v.f = f;
  unsigned r = v.u + 0x7fffu + ((v.u >> 16) & 1u);
  return (short)(r >> 16);
}

__device__ __forceinline__ unsigned pk2(float a, float b) {
#ifdef HAS_PK
  auto p = __builtin_amdgcn_cvt_pk_bf16_f32(a, b);
  return __builtin_bit_cast(unsigned, p);
#else
  return (unsigned)(unsigned short)f2bf(a) | ((unsigned)(unsigned short)f2bf(b) << 16);
#endif
}

// tanh-GELU with exp2-folded constants; |err| vs erf-gelu ~3e-4.
__device__ __forceinline__ float gelu_f(float x) {
  float z = x * (-2.3021991f - 0.10294200f * x * x);
  float e = __builtin_amdgcn_exp2f(z);
  return x * __builtin_amdgcn_rcpf(1.0f + e);
}

// ---------------------------------------------------------------------------
// Pack weights into bf16 MFMA B-fragment tiles (512 shorts each; lane l holds
// 8 bf16 = W[kt*32 + (l>>4)*8 + j][nt*16 + (l&15)]).
// ws (shorts): W1i [0,16384) | W1e [16384,49152) | W2 [49152,65536)
//              W3 [65536,81920) | Wu [81920,98304)
// ---------------------------------------------------------------------------
__global__ void pack_weights(const float* __restrict__ W1,
                             const float* __restrict__ W2,
                             const float* __restrict__ W3,
                             const float* __restrict__ Wu,
                             short* __restrict__ ws) {
  int tid = blockIdx.x * blockDim.x + threadIdx.x;
  if (tid >= 192 * 64) return;
  int lane = tid & 63;
  int tile = tid >> 6;
  const float* W; short* dst;
  if (tile < 32)       { W = W1;         dst = ws; }
  else if (tile < 96)  { W = W1 + 16384; dst = ws + 16384; tile -= 32; }
  else if (tile < 128) { W = W2;         dst = ws + 49152; tile -= 96; }
  else if (tile < 160) { W = W3;         dst = ws + 65536; tile -= 128; }
  else                 { W = Wu;         dst = ws + 81920; tile -= 160; }
  int kt = tile >> 3, nt = tile & 7;
  int n  = nt * 16 + (lane & 15);
  int k0 = kt * 32 + (lane >> 4) * 8;
  union { short s[8]; bf16x8 v; } u8;
#pragma unroll
  for (int j = 0; j < 8; j++) u8.s[j] = f2bf(W[(k0 + j) * 128 + n]);
  *reinterpret_cast<bf16x8*>(dst + (tile << 9) + lane * 8) = u8.v;
}

// ---------------------------------------------------------------------------
// Kernel 1: edge MLP, TWO nodes per block. 512 thr = 8 waves; wave w owns
// output cols [w*16, w*16+16) in every GEMM. M = 96 rows (48 edges x 2 nodes).
// Round-3 change: all W fragments hoisted to registers at entry (16 x 16B =
// 64 VGPR/wave) so GEMM loops are pure ds_read+MFMA; staging split into
// issue-pass -> accY MFMAs -> convert-pass to hide HBM latency. The previous
// VGPR_Count=40 left zero prefetch depth; budget at 6 waves/EU is 341.
// ---------------------------------------------------------------------------
__global__ __launch_bounds__(512, 6)
void node_update_kernel(const float* __restrict__ node_h,
                        const float* __restrict__ edge_h,
                        const int*   __restrict__ edge_index,
                        const short* __restrict__ wpack,
                        const float* __restrict__ b1,
                        const float* __restrict__ b2,
                        float* __restrict__ hs_out) {
  // LDS (bytes), 50048 total:
  //  [0,49152)      Xs 96x256 bf16 swizzled (node_j|edge_h); dead after GEMM1
  //  [24576,49152)  H1s 96x128 bf16 swizzled (overlays Xs; written post-barrier)
  //  [49152,49664)  nhb: node_i bf16 x256 (2 nodes)
  //  [49664,50048)  idx_s x96
  __shared__ __align__(16) char smem[50048];
  short* Xs    = (short*)smem;
  short* H1s   = (short*)(smem + 24576);
  short* nhb   = (short*)(smem + 49152);
  int*   idx_s = (int*)  (smem + 49664);

  const int tid  = threadIdx.x;
  const int n0   = blockIdx.x * 2;     // first node of the pair
  const int bb   = n0 >> 11;           // batch (pair never straddles: 2048 even)
  const int lane = tid & 63;
  const int wave = tid >> 6;           // 0..7
  const int lr   = lane & 15;
  const int lq   = lane >> 4;

  const short* W1i = wpack;
  const short* W1e = wpack + 16384;
  const short* W2p = wpack + 49152;

  // ---- hoist ALL weight fragments into registers (issue L2 loads first) ----
  bf16x8 w1i[4], w1e[8], w2f[4];
#pragma unroll
  for (int kt = 0; kt < 4; kt++)
    w1i[kt] = *reinterpret_cast<const bf16x8*>(W1i + ((kt * 8 + wave) << 9) + lane * 8);
#pragma unroll
  for (int kt = 0; kt < 8; kt++)
    w1e[kt] = *reinterpret_cast<const bf16x8*>(W1e + ((kt * 8 + wave) << 9) + lane * 8);
#pragma unroll
  for (int kt = 0; kt < 4; kt++)
    w2f[kt] = *reinterpret_cast<const bf16x8*>(W2p + ((kt * 8 + wave) << 9) + lane * 8);
  const int colw = wave * 16 + lr;
  const float b1v = b1[colw];
  const float b2v = b2[colw];

  // ---- phase 0: node_i bf16 (2 nodes) + neighbor indices (96) ----
  if (tid < 256) {
    nhb[tid] = f2bf(node_h[(size_t)n0 * Cn + tid]);
  } else if (tid < 352) {
    idx_s[tid - 256] = edge_index[n0 * Kn + (tid - 256)];
  }
  __syncthreads();

  // ---- stage X: pass 1 issues all 12 global loads into registers ----
  const int w  = tid & 31;   // 16B granule within row (0..15 node, 16..31 edge)
  const int rr = tid >> 5;   // 0..15
  float4 v0[6], v1[6];
#pragma unroll
  for (int k = 0; k < 6; k++) {
    int r = rr + k * 16;     // 0..95
    const float* src = (w < 16)
        ? node_h + (size_t)(bb * Nn + idx_s[r]) * Cn + w * 8
        : edge_h + ((size_t)n0 * Kn + r) * Cn + (w - 16) * 8;
    v0[k] = *reinterpret_cast<const float4*>(src);
    v1[k] = *reinterpret_cast<const float4*>(src + 4);
  }

  // ---- node_i row-vector MFMAs for both nodes (hide staging load latency) ----
  f32x4 accY[2] = {};   // [node]
  __builtin_amdgcn_s_setprio(1);
#pragma unroll
  for (int kt = 0; kt < 4; kt++) {
    bf16x8 avA = {}, avB = {};
    if (lr == 0) {
      avA = *reinterpret_cast<const bf16x8*>(&nhb[kt * 32 + lq * 8]);
      avB = *reinterpret_cast<const bf16x8*>(&nhb[128 + kt * 32 + lq * 8]);
    }
    accY[0] = __builtin_amdgcn_mfma_f32_16x16x32_bf16(avA, w1i[kt], accY[0], 0, 0, 0);
    accY[1] = __builtin_amdgcn_mfma_f32_16x16x32_bf16(avB, w1i[kt], accY[1], 0, 0, 0);
  }
  __builtin_amdgcn_s_setprio(0);

  // ---- stage X: pass 2 converts + LDS stores ----
#pragma unroll
  for (int k = 0; k < 6; k++) {
    int r = rr + k * 16;
    uint4 p;
    p.x = pk2(v0[k].x, v0[k].y); p.y = pk2(v0[k].z, v0[k].w);
    p.z = pk2(v1[k].x, v1[k].y); p.w = pk2(v1[k].z, v1[k].w);
    *reinterpret_cast<uint4*>(&Xs[r * 256 + ((w ^ (r & 7)) << 3)]) = p;
  }
  __syncthreads();

  // ---- GEMM1: (96x256) @ W1[128:384]; W in regs, pure ds_read+MFMA ----
  f32x4 acc[6] = {};
  __builtin_amdgcn_s_setprio(1);
#pragma unroll
  for (int kt = 0; kt < 8; kt++) {
    int sw = (((kt * 4 + lq) ^ (lr & 7)) << 3);
#pragma unroll
    for (int m = 0; m < 6; m++) {
      bf16x8 a = *reinterpret_cast<const bf16x8*>(&Xs[(m * 16 + lr) * 256 + sw]);
      acc[m] = __builtin_amdgcn_mfma_f32_16x16x32_bf16(a, w1e[kt], acc[m], 0, 0, 0);
    }
  }
  __builtin_amdgcn_s_setprio(0);
  __syncthreads();   // all Xs reads done before H1s (overlay) writes

  // ---- GEMM1 epilogue: +yi +b1, gelu, bf16 -> H1s ----
  {
    float yiA = __shfl(accY[0][0], lr) + b1v;
    float yiB = __shfl(accY[1][0], lr) + b1v;
    int g = colw >> 3, cl = colw & 7;
#pragma unroll
    for (int mt = 0; mt < 6; mt++) {
      float yi = (mt < 3) ? yiA : yiB;
      int r0 = mt * 16 + lq * 4;
      float g0 = gelu_f(acc[mt][0] + yi);
      float g1 = gelu_f(acc[mt][1] + yi);
      float g2 = gelu_f(acc[mt][2] + yi);
      float g3 = gelu_f(acc[mt][3] + yi);
      unsigned p01 = pk2(g0, g1), p23 = pk2(g2, g3);
      H1s[(r0 + 0) * 128 + ((g ^ ((r0 + 0) & 7)) << 3) + cl] = (short)(p01 & 0xffff);
      H1s[(r0 + 1) * 128 + ((g ^ ((r0 + 1) & 7)) << 3) + cl] = (short)(p01 >> 16);
      H1s[(r0 + 2) * 128 + ((g ^ ((r0 + 2) & 7)) << 3) + cl] = (short)(p23 & 0xffff);
      H1s[(r0 + 3) * 128 + ((g ^ ((r0 + 3) & 7)) << 3) + cl] = (short)(p23 >> 16);
    }
  }
  __syncthreads();

  // ---- GEMM2: (96x128) @ W2, fused gelu + column-sum; write hs f32 ----
  f32x4 acc2[6] = {};
  __builtin_amdgcn_s_setprio(1);
#pragma unroll
  for (int kt = 0; kt < 4; kt++) {
    int sw = (((kt * 4 + lq) ^ (lr & 7)) << 3);
#pragma unroll
    for (int m = 0; m < 6; m++) {
      bf16x8 a = *reinterpret_cast<const bf16x8*>(&H1s[(m * 16 + lr) * 128 + sw]);
      acc2[m] = __builtin_amdgcn_mfma_f32_16x16x32_bf16(a, w2f[kt], acc2[m], 0, 0, 0);
    }
  }
  __builtin_amdgcn_s_setprio(0);
  {
    float sA = 0.f, sB = 0.f;
#pragma unroll
    for (int mt = 0; mt < 3; mt++)
#pragma unroll
      for (int r = 0; r < 4; r++) {
        sA += gelu_f(acc2[mt][r] + b2v);
        sB += gelu_f(acc2[mt + 3][r] + b2v);
      }
    sA += __shfl_xor(sA, 16);
    sA += __shfl_xor(sA, 32);
    sB += __shfl_xor(sB, 16);
    sB += __shfl_xor(sB, 32);
    if (lq == 0) {
      hs_out[(size_t)n0 * Cn + colw]       = sA;
      hs_out[(size_t)(n0 + 1) * Cn + colw] = sB;
    }
  }
}

// ---------------------------------------------------------------------------
// Kernel 2 (tail, batched): 16 nodes per block.
// msg = (hs @ W3 + 48*b3)/30 ; x = nh + msg ; u = LN(x) ;
// y = nh + u@Wu + bu ; out = LN(y).  Matvecs are dense M=16 MFMA GEMMs.
// Reads hs from the out buffer, overwrites the same rows at the end.
// W3/Wu fragments hoisted to registers before staging (same trick as k1).
// ---------------------------------------------------------------------------
__global__ __launch_bounds__(256, 4)
void tail_kernel(const float* __restrict__ node_h,
                 const short* __restrict__ wpack,
                 const float* __restrict__ b3,
                 const float* __restrict__ bu,
                 const float* __restrict__ ln_g,
                 const float* __restrict__ ln_b,
                 float* __restrict__ out) {
  // LDS: hsB 16x128 bf16 swz [0,4096) | nhr 16x128 f32 [4096,12288)
  //      xs 16x132 f32 [12288,20736) | usB 16x128 bf16 swz [20736,24832)
  __shared__ __align__(16) char sm2[24832];
  short* hsB = (short*)sm2;
  float* nhr = (float*)(sm2 + 4096);
  float* xs  = (float*)(sm2 + 12288);
  short* usB = (short*)(sm2 + 20736);

  const int tid  = threadIdx.x;
  const int lane = tid & 63;
  const int wave = tid >> 6;
  const int lr   = lane & 15;
  const int lq   = lane >> 4;
  const int n0   = blockIdx.x * G2;

  const short* W3p = wpack + 65536;
  const short* Wup = wpack + 81920;

  // ---- hoist W3/Wu fragments (L2) into registers ----
  bf16x8 w3f[8], wuf[8];
#pragma unroll
  for (int kt = 0; kt < 4; kt++) {
    w3f[2 * kt + 0] = *reinterpret_cast<const bf16x8*>(W3p + ((kt * 8 + wave * 2 + 0) << 9) + lane * 8);
    w3f[2 * kt + 1] = *reinterpret_cast<const bf16x8*>(W3p + ((kt * 8 + wave * 2 + 1) << 9) + lane * 8);
    wuf[2 * kt + 0] = *reinterpret_cast<const bf16x8*>(Wup + ((kt * 8 + wave * 2 + 0) << 9) + lane * 8);
    wuf[2 * kt + 1] = *reinterpret_cast<const bf16x8*>(Wup + ((kt * 8 + wave * 2 + 1) << 9) + lane * 8);
  }

  // ---- stage node_h (f32) and hs (bf16, swizzled) ----
  {
    int row = tid >> 4, seg = tid & 15;
    const float* p = node_h + (size_t)(n0 + row) * Cn + seg * 8;
    float4 a0 = *reinterpret_cast<const float4*>(p);
    float4 a1 = *reinterpret_cast<const float4*>(p + 4);
    *reinterpret_cast<float4*>(&nhr[row * 128 + seg * 8])     = a0;
    *reinterpret_cast<float4*>(&nhr[row * 128 + seg * 8 + 4]) = a1;
    const float* q = out + (size_t)(n0 + row) * Cn + seg * 8;  // hs scratch
    float4 c0 = *reinterpret_cast<const float4*>(q);
    float4 c1 = *reinterpret_cast<const float4*>(q + 4);
    uint4 pk;
    pk.x = pk2(c0.x, c0.y); pk.y = pk2(c0.z, c0.w);
    pk.z = pk2(c1.x, c1.y); pk.w = pk2(c1.z, c1.w);
    *reinterpret_cast<uint4*>(&hsB[row * 128 + ((seg ^ (row & 7)) << 3)]) = pk;
  }
  __syncthreads();

  // ---- msg GEMM (M=16): hs @ W3 ; x = nh + (.+48*b3)/30 -> xs ----
  f32x4 am[2] = {};
#pragma unroll
  for (int kt = 0; kt < 4; kt++) {
    bf16x8 av = *reinterpret_cast<const bf16x8*>(&hsB[lr * 128 + (((kt * 4 + lq) ^ (lr & 7)) << 3)]);
    am[0] = __builtin_amdgcn_mfma_f32_16x16x32_bf16(av, w3f[2 * kt + 0], am[0], 0, 0, 0);
    am[1] = __builtin_amdgcn_mfma_f32_16x16x32_bf16(av, w3f[2 * kt + 1], am[1], 0, 0, 0);
  }
#pragma unroll
  for (int j = 0; j < 2; j++) {
    int col = (wave * 2 + j) * 16 + lr;
    float bb = 48.0f * b3[col];
#pragma unroll
    for (int r = 0; r < 4; r++) {
      int row = lq * 4 + r;
      xs[row * 132 + col] = nhr[row * 128 + col] + (am[j][r] + bb) * (1.0f / 30.0f);
    }
  }
  __syncthreads();

  // ---- LN1 -> usB (bf16 swz). Wave handles 4 rows; lane owns cols lane,lane+64.
  const float lg1 = ln_g[lane],      lb1v = ln_b[lane];
  const float lg2 = ln_g[lane + 64], lb2v = ln_b[lane + 64];
#pragma unroll
  for (int s = 0; s < 4; s++) {
    int row = wave * 4 + s;
    float v1 = xs[row * 132 + lane];
    float v2 = xs[row * 132 + lane + 64];
    float s1 = v1 + v2, s2 = v1 * v1 + v2 * v2;
#pragma unroll
    for (int off = 32; off >= 1; off >>= 1) {
      s1 += __shfl_xor(s1, off);
      s2 += __shfl_xor(s2, off);
    }
    float mu = s1 * (1.f / 128.f);
    float var = s2 * (1.f / 128.f) - mu * mu;
    float rstd = rsqrtf(var + 1e-5f);
    unsigned u12 = pk2((v1 - mu) * rstd * lg1 + lb1v,
                       (v2 - mu) * rstd * lg2 + lb2v);
    int sw = (row & 7);
    usB[row * 128 + (((lane >> 3) ^ sw) << 3) + (lane & 7)]       = (short)(u12 & 0xffff);
    usB[row * 128 + ((((lane >> 3) + 8) ^ sw) << 3) + (lane & 7)] = (short)(u12 >> 16);
  }
  __syncthreads();

  // ---- upd GEMM (M=16): u @ Wu ; y = nh + . + bu -> xs ----
  f32x4 au[2] = {};
#pragma unroll
  for (int kt = 0; kt < 4; kt++) {
    bf16x8 av = *reinterpret_cast<const bf16x8*>(&usB[lr * 128 + (((kt * 4 + lq) ^ (lr & 7)) << 3)]);
    au[0] = __builtin_amdgcn_mfma_f32_16x16x32_bf16(av, wuf[2 * kt + 0], au[0], 0, 0, 0);
    au[1] = __builtin_amdgcn_mfma_f32_16x16x32_bf16(av, wuf[2 * kt + 1], au[1], 0, 0, 0);
  }
  __syncthreads();   // xs LN1 reads done before overwrite
#pragma unroll
  for (int j = 0; j < 2; j++) {
    int col = (wave * 2 + j) * 16 + lr;
    float bb = bu[col];
#pragma unroll
    for (int r = 0; r < 4; r++) {
      int row = lq * 4 + r;
      xs[row * 132 + col] = nhr[row * 128 + col] + au[j][r] + bb;
    }
  }
  __syncthreads();

  // ---- LN2 -> out ----
#pragma unroll
  for (int s = 0; s < 4; s++) {
    int row = wave * 4 + s;
    float v1 = xs[row * 132 + lane];
    float v2 = xs[row * 132 + lane + 64];
    float s1 = v1 + v2, s2 = v1 * v1 + v2 * v2;
#pragma unroll
    for (int off = 32; off >= 1; off >>= 1) {
      s1 += __shfl_xor(s1, off);
      s2 += __shfl_xor(s2, off);
    }
    float mu = s1 * (1.f / 128.f);
    float var = s2 * (1.f / 128.f) - mu * mu;
    float rstd = rsqrtf(var + 1e-5f);
    out[(size_t)(n0 + row) * Cn + lane]      = (v1 - mu) * rstd * lg1 + lb1v;
    out[(size_t)(n0 + row) * Cn + lane + 64] = (v2 - mu) * rstd * lg2 + lb2v;
  }
}

extern "C" void kernel_launch(void* const* d_in, const int* in_sizes, int n_in,
                              void* d_out, int out_size, void* d_ws, size_t ws_size,
                              hipStream_t stream) {
  const float* node_h     = (const float*)d_in[0];
  const float* edge_h     = (const float*)d_in[1];
  const int*   edge_index = (const int*)  d_in[2];
  const float* W1 = (const float*)d_in[3];
  const float* b1 = (const float*)d_in[4];
  const float* W2 = (const float*)d_in[5];
  const float* b2 = (const float*)d_in[6];
  const float* W3 = (const float*)d_in[7];
  const float* b3 = (const float*)d_in[8];
  const float* Wu = (const float*)d_in[9];
  const float* bu = (const float*)d_in[10];
  const float* ln_g = (const float*)d_in[11];
  const float* ln_b = (const float*)d_in[12];
  float* out   = (float*)d_out;
  short* wpack = (short*)d_ws;   // 192 KiB

  pack_weights<<<48, 256, 0, stream>>>(W1, W2, W3, Wu, wpack);
  node_update_kernel<<<(Bn * Nn) / 2, 512, 0, stream>>>(
      node_h, edge_h, edge_index, wpack, b1, b2, out);
  tail_kernel<<<(Bn * Nn) / G2, 256, 0, stream>>>(
      node_h, wpack, b3, bu, ln_g, ln_b, out);
}

// Round 4
// 209.025 us; speedup vs baseline: 1.3499x; 1.3499x over previous
//
#include <hip/hip_runtime.h>
#include <hip/hip_bf16.h>
#include <math.h>

// Problem constants
#define Bn   2
#define Nn   2048
#define Kn   48
#define Cn   128
#define G2   16     // nodes per block in the tail kernel

typedef short bf16x8 __attribute__((ext_vector_type(8)));
typedef float f32x4  __attribute__((ext_vector_type(4)));

#if __has_builtin(__builtin_amdgcn_cvt_pk_bf16_f32)
#define HAS_PK 1
#endif

__device__ __forceinline__ short f2bf(float f) {
  union { float f; unsigned u; } v; v.f = f;
  unsigned r = v.u + 0x7fffu + ((v.u >> 16) & 1u);
  return (short)(r >> 16);
}

__device__ __forceinline__ unsigned pk2(float a, float b) {
#ifdef HAS_PK
  auto p = __builtin_amdgcn_cvt_pk_bf16_f32(a, b);
  return __builtin_bit_cast(unsigned, p);
#else
  return (unsigned)(unsigned short)f2bf(a) | ((unsigned)(unsigned short)f2bf(b) << 16);
#endif
}

// tanh-GELU with exp2-folded constants; |err| vs erf-gelu ~3e-4.
__device__ __forceinline__ float gelu_f(float x) {
  float z = x * (-2.3021991f - 0.10294200f * x * x);
  float e = __builtin_amdgcn_exp2f(z);
  return x * __builtin_amdgcn_rcpf(1.0f + e);
}

// ---------------------------------------------------------------------------
// Pack weights into bf16 MFMA B-fragment tiles (512 shorts each; lane l holds
// 8 bf16 = W[kt*32 + (l>>4)*8 + j][nt*16 + (l&15)]).
// ws (shorts): W1i [0,16384) | W1e [16384,49152) | W2 [49152,65536)
//              W3 [65536,81920) | Wu [81920,98304)
// ---------------------------------------------------------------------------
__global__ void pack_weights(const float* __restrict__ W1,
                             const float* __restrict__ W2,
                             const float* __restrict__ W3,
                             const float* __restrict__ Wu,
                             short* __restrict__ ws) {
  int tid = blockIdx.x * blockDim.x + threadIdx.x;
  if (tid >= 192 * 64) return;
  int lane = tid & 63;
  int tile = tid >> 6;
  const float* W; short* dst;
  if (tile < 32)       { W = W1;         dst = ws; }
  else if (tile < 96)  { W = W1 + 16384; dst = ws + 16384; tile -= 32; }
  else if (tile < 128) { W = W2;         dst = ws + 49152; tile -= 96; }
  else if (tile < 160) { W = W3;         dst = ws + 65536; tile -= 128; }
  else                 { W = Wu;         dst = ws + 81920; tile -= 160; }
  int kt = tile >> 3, nt = tile & 7;
  int n  = nt * 16 + (lane & 15);
  int k0 = kt * 32 + (lane >> 4) * 8;
  union { short s[8]; bf16x8 v; } u8;
#pragma unroll
  for (int j = 0; j < 8; j++) u8.s[j] = f2bf(W[(k0 + j) * 128 + n]);
  *reinterpret_cast<bf16x8*>(dst + (tile << 9) + lane * 8) = u8.v;
}

// ---------------------------------------------------------------------------
// Kernel 1: edge MLP, TWO nodes per block. 512 thr = 8 waves; wave w owns
// output cols [w*16, w*16+16). M = 96 rows (48 edges x 2 nodes).
// Round-4 change: GEMM1 split along K. Stage node_j half (96x128 bf16),
// GEMM1a (kt 0-3), then OVERWRITE the same LDS with the edge half and run
// GEMM1b (kt 4-7) with acc held in registers. LDS 50KB -> 24.9KB, so the
// occupancy cap moves from LDS (3 blk/CU) to the 32-wave limit (4 blk/CU).
// __launch_bounds__(512,8) pins VGPR<=64 to guarantee the 4th block.
// ---------------------------------------------------------------------------
__global__ __launch_bounds__(512, 8)
void node_update_kernel(const float* __restrict__ node_h,
                        const float* __restrict__ edge_h,
                        const int*   __restrict__ edge_index,
                        const short* __restrict__ wpack,
                        const float* __restrict__ b1,
                        const float* __restrict__ b2,
                        float* __restrict__ hs_out) {
  // LDS (bytes), 25472 total:
  //  [0,24576)      Xs 96x128 bf16 swizzled (node_j half, then edge half,
  //                 then H1s overlays the same extents)
  //  [24576,25088)  nhb: node_i bf16 x256 (2 nodes)
  //  [25088,25472)  idx_s x96
  __shared__ __align__(16) char smem[25472];
  short* Xs    = (short*)smem;
  short* H1s   = (short*)smem;           // full overlay of Xs
  short* nhb   = (short*)(smem + 24576);
  int*   idx_s = (int*)  (smem + 25088);

  const int tid  = threadIdx.x;
  const int n0   = blockIdx.x * 2;     // first node of the pair
  const int bb   = n0 >> 11;           // batch (pair never straddles: 2048 even)
  const int lane = tid & 63;
  const int wave = tid >> 6;           // 0..7
  const int lr   = lane & 15;
  const int lq   = lane >> 4;

  const short* W1i = wpack;
  const short* W1e = wpack + 16384;
  const short* W2p = wpack + 49152;

  // ---- phase 0: node_i bf16 (2 nodes) + neighbor indices (96) ----
  if (tid < 256) {
    nhb[tid] = f2bf(node_h[(size_t)n0 * Cn + tid]);
  } else if (tid < 352) {
    idx_s[tid - 256] = edge_index[n0 * Kn + (tid - 256)];
  }
  __syncthreads();

  // ---- stage node_j half: Xs[96][128] bf16, 16B-granule XOR swizzle ----
  // 512 threads = 32 rows x 16 granules per round; 3 rounds.
  const int gw = tid & 15;   // granule within row
  const int gr = tid >> 4;   // 0..31
#pragma unroll
  for (int k = 0; k < 3; k++) {
    int r = gr + k * 32;     // 0..95
    const float* src = node_h + (size_t)(bb * Nn + idx_s[r]) * Cn + gw * 8;
    float4 v0 = *reinterpret_cast<const float4*>(src);
    float4 v1 = *reinterpret_cast<const float4*>(src + 4);
    uint4 p;
    p.x = pk2(v0.x, v0.y); p.y = pk2(v0.z, v0.w);
    p.z = pk2(v1.x, v1.y); p.w = pk2(v1.z, v1.w);
    *reinterpret_cast<uint4*>(&Xs[r * 128 + ((gw ^ (r & 7)) << 3)]) = p;
  }
  __syncthreads();

  // ---- node_i row-vector MFMAs for both nodes ----
  f32x4 accY[2] = {};   // [node]
#pragma unroll
  for (int kt = 0; kt < 4; kt++) {
    bf16x8 avA = {}, avB = {};
    if (lr == 0) {
      avA = *reinterpret_cast<const bf16x8*>(&nhb[kt * 32 + lq * 8]);
      avB = *reinterpret_cast<const bf16x8*>(&nhb[128 + kt * 32 + lq * 8]);
    }
    bf16x8 bv = *reinterpret_cast<const bf16x8*>(W1i + ((kt * 8 + wave) << 9) + lane * 8);
    accY[0] = __builtin_amdgcn_mfma_f32_16x16x32_bf16(avA, bv, accY[0], 0, 0, 0);
    accY[1] = __builtin_amdgcn_mfma_f32_16x16x32_bf16(avB, bv, accY[1], 0, 0, 0);
  }

  // ---- GEMM1a: (96x128 node_j) @ W1[128:256] (kt 0-3) ----
  f32x4 acc[6] = {};
#pragma unroll
  for (int kt = 0; kt < 4; kt++) {
    bf16x8 bf = *reinterpret_cast<const bf16x8*>(W1e + ((kt * 8 + wave) << 9) + lane * 8);
    int sw = (((kt * 4 + lq) ^ (lr & 7)) << 3);
#pragma unroll
    for (int m = 0; m < 6; m++) {
      bf16x8 a = *reinterpret_cast<const bf16x8*>(&Xs[(m * 16 + lr) * 128 + sw]);
      acc[m] = __builtin_amdgcn_mfma_f32_16x16x32_bf16(a, bf, acc[m], 0, 0, 0);
    }
  }
  __syncthreads();   // Xs node-half reads done before edge overwrite

  // ---- stage edge half into the same Xs ----
#pragma unroll
  for (int k = 0; k < 3; k++) {
    int r = gr + k * 32;     // 0..95 (edge r of the pair: n0*Kn + r)
    const float* src = edge_h + ((size_t)n0 * Kn + r) * Cn + gw * 8;
    float4 v0 = *reinterpret_cast<const float4*>(src);
    float4 v1 = *reinterpret_cast<const float4*>(src + 4);
    uint4 p;
    p.x = pk2(v0.x, v0.y); p.y = pk2(v0.z, v0.w);
    p.z = pk2(v1.x, v1.y); p.w = pk2(v1.z, v1.w);
    *reinterpret_cast<uint4*>(&Xs[r * 128 + ((gw ^ (r & 7)) << 3)]) = p;
  }
  __syncthreads();

  // ---- GEMM1b: (96x128 edge) @ W1[256:384] (kt 4-7) ----
#pragma unroll
  for (int kt = 4; kt < 8; kt++) {
    bf16x8 bf = *reinterpret_cast<const bf16x8*>(W1e + ((kt * 8 + wave) << 9) + lane * 8);
    int sw = ((((kt - 4) * 4 + lq) ^ (lr & 7)) << 3);
#pragma unroll
    for (int m = 0; m < 6; m++) {
      bf16x8 a = *reinterpret_cast<const bf16x8*>(&Xs[(m * 16 + lr) * 128 + sw]);
      acc[m] = __builtin_amdgcn_mfma_f32_16x16x32_bf16(a, bf, acc[m], 0, 0, 0);
    }
  }
  __syncthreads();   // Xs edge reads done before H1s (overlay) writes

  // ---- GEMM1 epilogue: +yi +b1, gelu, bf16 -> H1s ----
  {
    int col = wave * 16 + lr;
    float yiA = __shfl(accY[0][0], lr) + b1[col];
    float yiB = __shfl(accY[1][0], lr) + b1[col];
    int g = col >> 3, cl = col & 7;
#pragma unroll
    for (int mt = 0; mt < 6; mt++) {
      float yi = (mt < 3) ? yiA : yiB;
      int r0 = mt * 16 + lq * 4;
      float g0 = gelu_f(acc[mt][0] + yi);
      float g1 = gelu_f(acc[mt][1] + yi);
      float g2 = gelu_f(acc[mt][2] + yi);
      float g3 = gelu_f(acc[mt][3] + yi);
      unsigned p01 = pk2(g0, g1), p23 = pk2(g2, g3);
      H1s[(r0 + 0) * 128 + ((g ^ ((r0 + 0) & 7)) << 3) + cl] = (short)(p01 & 0xffff);
      H1s[(r0 + 1) * 128 + ((g ^ ((r0 + 1) & 7)) << 3) + cl] = (short)(p01 >> 16);
      H1s[(r0 + 2) * 128 + ((g ^ ((r0 + 2) & 7)) << 3) + cl] = (short)(p23 & 0xffff);
      H1s[(r0 + 3) * 128 + ((g ^ ((r0 + 3) & 7)) << 3) + cl] = (short)(p23 >> 16);
    }
  }
  __syncthreads();

  // ---- GEMM2: (96x128) @ W2, fused gelu + column-sum; write hs f32 ----
  f32x4 acc2[6] = {};
#pragma unroll
  for (int kt = 0; kt < 4; kt++) {
    bf16x8 bf = *reinterpret_cast<const bf16x8*>(W2p + ((kt * 8 + wave) << 9) + lane * 8);
    int sw = (((kt * 4 + lq) ^ (lr & 7)) << 3);
#pragma unroll
    for (int m = 0; m < 6; m++) {
      bf16x8 a = *reinterpret_cast<const bf16x8*>(&H1s[(m * 16 + lr) * 128 + sw]);
      acc2[m] = __builtin_amdgcn_mfma_f32_16x16x32_bf16(a, bf, acc2[m], 0, 0, 0);
    }
  }
  {
    int col = wave * 16 + lr;
    float bias = b2[col];
    float sA = 0.f, sB = 0.f;
#pragma unroll
    for (int mt = 0; mt < 3; mt++)
#pragma unroll
      for (int r = 0; r < 4; r++) {
        sA += gelu_f(acc2[mt][r] + bias);
        sB += gelu_f(acc2[mt + 3][r] + bias);
      }
    sA += __shfl_xor(sA, 16);
    sA += __shfl_xor(sA, 32);
    sB += __shfl_xor(sB, 16);
    sB += __shfl_xor(sB, 32);
    if (lq == 0) {
      hs_out[(size_t)n0 * Cn + col]       = sA;
      hs_out[(size_t)(n0 + 1) * Cn + col] = sB;
    }
  }
}

// ---------------------------------------------------------------------------
// Kernel 2 (tail, batched): 16 nodes per block.
// msg = (hs @ W3 + 48*b3)/30 ; x = nh + msg ; u = LN(x) ;
// y = nh + u@Wu + bu ; out = LN(y).  Matvecs are dense M=16 MFMA GEMMs.
// Reads hs from the out buffer, overwrites the same rows at the end.
// ---------------------------------------------------------------------------
__global__ __launch_bounds__(256, 4)
void tail_kernel(const float* __restrict__ node_h,
                 const short* __restrict__ wpack,
                 const float* __restrict__ b3,
                 const float* __restrict__ bu,
                 const float* __restrict__ ln_g,
                 const float* __restrict__ ln_b,
                 float* __restrict__ out) {
  // LDS: hsB 16x128 bf16 swz [0,4096) | nhr 16x128 f32 [4096,12288)
  //      xs 16x132 f32 [12288,20736) | usB 16x128 bf16 swz [20736,24832)
  __shared__ __align__(16) char sm2[24832];
  short* hsB = (short*)sm2;
  float* nhr = (float*)(sm2 + 4096);
  float* xs  = (float*)(sm2 + 12288);
  short* usB = (short*)(sm2 + 20736);

  const int tid  = threadIdx.x;
  const int lane = tid & 63;
  const int wave = tid >> 6;
  const int lr   = lane & 15;
  const int lq   = lane >> 4;
  const int n0   = blockIdx.x * G2;

  const short* W3p = wpack + 65536;
  const short* Wup = wpack + 81920;

  // ---- stage node_h (f32) and hs (bf16, swizzled) ----
  {
    int row = tid >> 4, seg = tid & 15;
    const float* p = node_h + (size_t)(n0 + row) * Cn + seg * 8;
    float4 a0 = *reinterpret_cast<const float4*>(p);
    float4 a1 = *reinterpret_cast<const float4*>(p + 4);
    *reinterpret_cast<float4*>(&nhr[row * 128 + seg * 8])     = a0;
    *reinterpret_cast<float4*>(&nhr[row * 128 + seg * 8 + 4]) = a1;
    const float* q = out + (size_t)(n0 + row) * Cn + seg * 8;  // hs scratch
    float4 c0 = *reinterpret_cast<const float4*>(q);
    float4 c1 = *reinterpret_cast<const float4*>(q + 4);
    uint4 pk;
    pk.x = pk2(c0.x, c0.y); pk.y = pk2(c0.z, c0.w);
    pk.z = pk2(c1.x, c1.y); pk.w = pk2(c1.z, c1.w);
    *reinterpret_cast<uint4*>(&hsB[row * 128 + ((seg ^ (row & 7)) << 3)]) = pk;
  }
  __syncthreads();

  // ---- msg GEMM (M=16): hs @ W3 ; x = nh + (.+48*b3)/30 -> xs ----
  f32x4 am[2] = {};
#pragma unroll
  for (int kt = 0; kt < 4; kt++) {
    bf16x8 av = *reinterpret_cast<const bf16x8*>(&hsB[lr * 128 + (((kt * 4 + lq) ^ (lr & 7)) << 3)]);
    bf16x8 bv0 = *reinterpret_cast<const bf16x8*>(W3p + ((kt * 8 + wave * 2 + 0) << 9) + lane * 8);
    bf16x8 bv1 = *reinterpret_cast<const bf16x8*>(W3p + ((kt * 8 + wave * 2 + 1) << 9) + lane * 8);
    am[0] = __builtin_amdgcn_mfma_f32_16x16x32_bf16(av, bv0, am[0], 0, 0, 0);
    am[1] = __builtin_amdgcn_mfma_f32_16x16x32_bf16(av, bv1, am[1], 0, 0, 0);
  }
#pragma unroll
  for (int j = 0; j < 2; j++) {
    int col = (wave * 2 + j) * 16 + lr;
    float bb = 48.0f * b3[col];
#pragma unroll
    for (int r = 0; r < 4; r++) {
      int row = lq * 4 + r;
      xs[row * 132 + col] = nhr[row * 128 + col] + (am[j][r] + bb) * (1.0f / 30.0f);
    }
  }
  __syncthreads();

  // ---- LN1 -> usB (bf16 swz). Wave handles 4 rows; lane owns cols lane,lane+64.
  const float lg1 = ln_g[lane],      lb1v = ln_b[lane];
  const float lg2 = ln_g[lane + 64], lb2v = ln_b[lane + 64];
#pragma unroll
  for (int s = 0; s < 4; s++) {
    int row = wave * 4 + s;
    float v1 = xs[row * 132 + lane];
    float v2 = xs[row * 132 + lane + 64];
    float s1 = v1 + v2, s2 = v1 * v1 + v2 * v2;
#pragma unroll
    for (int off = 32; off >= 1; off >>= 1) {
      s1 += __shfl_xor(s1, off);
      s2 += __shfl_xor(s2, off);
    }
    float mu = s1 * (1.f / 128.f);
    float var = s2 * (1.f / 128.f) - mu * mu;
    float rstd = rsqrtf(var + 1e-5f);
    unsigned u12 = pk2((v1 - mu) * rstd * lg1 + lb1v,
                       (v2 - mu) * rstd * lg2 + lb2v);
    int sw = (row & 7);
    usB[row * 128 + (((lane >> 3) ^ sw) << 3) + (lane & 7)]       = (short)(u12 & 0xffff);
    usB[row * 128 + ((((lane >> 3) + 8) ^ sw) << 3) + (lane & 7)] = (short)(u12 >> 16);
  }
  __syncthreads();

  // ---- upd GEMM (M=16): u @ Wu ; y = nh + . + bu -> xs ----
  f32x4 au[2] = {};
#pragma unroll
  for (int kt = 0; kt < 4; kt++) {
    bf16x8 av = *reinterpret_cast<const bf16x8*>(&usB[lr * 128 + (((kt * 4 + lq) ^ (lr & 7)) << 3)]);
    bf16x8 bv0 = *reinterpret_cast<const bf16x8*>(Wup + ((kt * 8 + wave * 2 + 0) << 9) + lane * 8);
    bf16x8 bv1 = *reinterpret_cast<const bf16x8*>(Wup + ((kt * 8 + wave * 2 + 1) << 9) + lane * 8);
    au[0] = __builtin_amdgcn_mfma_f32_16x16x32_bf16(av, bv0, au[0], 0, 0, 0);
    au[1] = __builtin_amdgcn_mfma_f32_16x16x32_bf16(av, bv1, au[1], 0, 0, 0);
  }
  __syncthreads();   // xs LN1 reads done before overwrite
#pragma unroll
  for (int j = 0; j < 2; j++) {
    int col = (wave * 2 + j) * 16 + lr;
    float bb = bu[col];
#pragma unroll
    for (int r = 0; r < 4; r++) {
      int row = lq * 4 + r;
      xs[row * 132 + col] = nhr[row * 128 + col] + au[j][r] + bb;
    }
  }
  __syncthreads();

  // ---- LN2 -> out ----
#pragma unroll
  for (int s = 0; s < 4; s++) {
    int row = wave * 4 + s;
    float v1 = xs[row * 132 + lane];
    float v2 = xs[row * 132 + lane + 64];
    float s1 = v1 + v2, s2 = v1 * v1 + v2 * v2;
#pragma unroll
    for (int off = 32; off >= 1; off >>= 1) {
      s1 += __shfl_xor(s1, off);
      s2 += __shfl_xor(s2, off);
    }
    float mu = s1 * (1.f / 128.f);
    float var = s2 * (1.f / 128.f) - mu * mu;
    float rstd = rsqrtf(var + 1e-5f);
    out[(size_t)(n0 + row) * Cn + lane]      = (v1 - mu) * rstd * lg1 + lb1v;
    out[(size_t)(n0 + row) * Cn + lane + 64] = (v2 - mu) * rstd * lg2 + lb2v;
  }
}

extern "C" void kernel_launch(void* const* d_in, const int* in_sizes, int n_in,
                              void* d_out, int out_size, void* d_ws, size_t ws_size,
                              hipStream_t stream) {
  const float* node_h     = (const float*)d_in[0];
  const float* edge_h     = (const float*)d_in[1];
  const int*   edge_index = (const int*)  d_in[2];
  const float* W1 = (const float*)d_in[3];
  const float* b1 = (const float*)d_in[4];
  const float* W2 = (const float*)d_in[5];
  const float* b2 = (const float*)d_in[6];
  const float* W3 = (const float*)d_in[7];
  const float* b3 = (const float*)d_in[8];
  const float* Wu = (const float*)d_in[9];
  const float* bu = (const float*)d_in[10];
  const float* ln_g = (const float*)d_in[11];
  const float* ln_b = (const float*)d_in[12];
  float* out   = (float*)d_out;
  short* wpack = (short*)d_ws;   // 192 KiB

  pack_weights<<<48, 256, 0, stream>>>(W1, W2, W3, Wu, wpack);
  node_update_kernel<<<(Bn * Nn) / 2, 512, 0, stream>>>(
      node_h, edge_h, edge_index, wpack, b1, b2, out);
  tail_kernel<<<(Bn * Nn) / G2, 256, 0, stream>>>(
      node_h, wpack, b3, bu, ln_g, ln_b, out);
}

// Round 5
// 202.722 us; speedup vs baseline: 1.3919x; 1.0311x over previous
//
#include <hip/hip_runtime.h>
#include <hip/hip_bf16.h>
#include <math.h>

// Problem constants
#define Bn   2
#define Nn   2048
#define Kn   48
#define Cn   128
#define G2   16     // nodes per block in the tail kernel

typedef short bf16x8 __attribute__((ext_vector_type(8)));
typedef float f32x4  __attribute__((ext_vector_type(4)));

#if __has_builtin(__builtin_amdgcn_cvt_pk_bf16_f32)
#define HAS_PK 1
#endif

__device__ __forceinline__ short f2bf(float f) {
  union { float f; unsigned u; } v; v.f = f;
  unsigned r = v.u + 0x7fffu + ((v.u >> 16) & 1u);
  return (short)(r >> 16);
}

__device__ __forceinline__ unsigned pk2(float a, float b) {
#ifdef HAS_PK
  auto p = __builtin_amdgcn_cvt_pk_bf16_f32(a, b);
  return __builtin_bit_cast(unsigned, p);
#else
  return (unsigned)(unsigned short)f2bf(a) | ((unsigned)(unsigned short)f2bf(b) << 16);
#endif
}

// tanh-GELU with exp2-folded constants; |err| vs erf-gelu ~3e-4.
__device__ __forceinline__ float gelu_f(float x) {
  float z = x * (-2.3021991f - 0.10294200f * x * x);
  float e = __builtin_amdgcn_exp2f(z);
  return x * __builtin_amdgcn_rcpf(1.0f + e);
}

// ---------------------------------------------------------------------------
// Pack weights into bf16 MFMA B-fragment tiles (512 shorts each; lane l holds
// 8 bf16 = W[kt*32 + (l>>4)*8 + j][nt*16 + (l&15)]).
// ws (shorts): W1i [0,16384) | W1e [16384,49152) | W2 [49152,65536)
//              W3 [65536,81920) | Wu [81920,98304)
// ---------------------------------------------------------------------------
__global__ void pack_weights(const float* __restrict__ W1,
                             const float* __restrict__ W2,
                             const float* __restrict__ W3,
                             const float* __restrict__ Wu,
                             short* __restrict__ ws) {
  int tid = blockIdx.x * blockDim.x + threadIdx.x;
  if (tid >= 192 * 64) return;
  int lane = tid & 63;
  int tile = tid >> 6;
  const float* W; short* dst;
  if (tile < 32)       { W = W1;         dst = ws; }
  else if (tile < 96)  { W = W1 + 16384; dst = ws + 16384; tile -= 32; }
  else if (tile < 128) { W = W2;         dst = ws + 49152; tile -= 96; }
  else if (tile < 160) { W = W3;         dst = ws + 65536; tile -= 128; }
  else                 { W = Wu;         dst = ws + 81920; tile -= 160; }
  int kt = tile >> 3, nt = tile & 7;
  int n  = nt * 16 + (lane & 15);
  int k0 = kt * 32 + (lane >> 4) * 8;
  union { short s[8]; bf16x8 v; } u8;
#pragma unroll
  for (int j = 0; j < 8; j++) u8.s[j] = f2bf(W[(k0 + j) * 128 + n]);
  *reinterpret_cast<bf16x8*>(dst + (tile << 9) + lane * 8) = u8.v;
}

// ---------------------------------------------------------------------------
// Kernel 1: edge MLP, TWO nodes per block. 512 thr = 8 waves; wave w owns
// output cols [w*16, w*16+16). M = 96 rows (48 edges x 2 nodes). K-split
// GEMM1 (node_j half, then edge half in the same 24.5KB LDS buffer).
// Round-5 change (T14 issue-early/write-late): the edge-half global loads
// are ISSUED before GEMM1a and converted/written after its barrier, so
// their HBM latency hides under 24 MFMAs + 24 ds_reads; the node_j gather
// issues before the accY MFMA phase. W fragments consumed during those
// phases (w1i, w1a) are hoisted AHEAD of the data loads because vmcnt
// retires in order (a W-load issued after the edge loads would chain its
// consumer wait behind the whole edge stream). accY is reduced to yiA/yiB
// immediately to free registers. Peak live ~78 VGPR -> bounds (512,6)
// (cap 85, 3 blk/CU = 24 waves/CU; r2-vs-r4 showed 24 vs 32 waves is
// performance-neutral here).
// ---------------------------------------------------------------------------
__global__ __launch_bounds__(512, 6)
void node_update_kernel(const float* __restrict__ node_h,
                        const float* __restrict__ edge_h,
                        const int*   __restrict__ edge_index,
                        const short* __restrict__ wpack,
                        const float* __restrict__ b1,
                        const float* __restrict__ b2,
                        float* __restrict__ hs_out) {
  // LDS (bytes), 25472 total:
  //  [0,24576)      Xs 96x128 bf16 swizzled (node_j half, then edge half,
  //                 then H1s overlays the same extents)
  //  [24576,25088)  nhb: node_i bf16 x256 (2 nodes)
  //  [25088,25472)  idx_s x96
  __shared__ __align__(16) char smem[25472];
  short* Xs    = (short*)smem;
  short* H1s   = (short*)smem;           // full overlay of Xs
  short* nhb   = (short*)(smem + 24576);
  int*   idx_s = (int*)  (smem + 25088);

  const int tid  = threadIdx.x;
  const int n0   = blockIdx.x * 2;     // first node of the pair
  const int bb   = n0 >> 11;           // batch (pair never straddles: 2048 even)
  const int lane = tid & 63;
  const int wave = tid >> 6;           // 0..7
  const int lr   = lane & 15;
  const int lq   = lane >> 4;

  const short* W1i = wpack;
  const short* W1e = wpack + 16384;
  const short* W2p = wpack + 49152;

  // ---- hoist W1i fragments + biases (issued before any data gather) ----
  bf16x8 w1i[4];
#pragma unroll
  for (int kt = 0; kt < 4; kt++)
    w1i[kt] = *reinterpret_cast<const bf16x8*>(W1i + ((kt * 8 + wave) << 9) + lane * 8);
  const int colw = wave * 16 + lr;
  const float b1v = b1[colw];
  const float b2v = b2[colw];

  // ---- phase 0: node_i bf16 (2 nodes) + neighbor indices (96) ----
  if (tid < 256) {
    nhb[tid] = f2bf(node_h[(size_t)n0 * Cn + tid]);
  } else if (tid < 352) {
    idx_s[tid - 256] = edge_index[n0 * Kn + (tid - 256)];
  }
  __syncthreads();

  const int gw = tid & 15;   // granule within row
  const int gr = tid >> 4;   // 0..31

  // ---- ISSUE node_j gather into registers (latency hidden under accY) ----
  float4 na[3], nb[3];
#pragma unroll
  for (int k = 0; k < 3; k++) {
    int r = gr + k * 32;     // 0..95
    const float* src = node_h + (size_t)(bb * Nn + idx_s[r]) * Cn + gw * 8;
    na[k] = *reinterpret_cast<const float4*>(src);
    nb[k] = *reinterpret_cast<const float4*>(src + 4);
  }

  // ---- node_i row-vector MFMAs for both nodes (W1i already in regs) ----
  f32x4 accY[2] = {};   // [node]
#pragma unroll
  for (int kt = 0; kt < 4; kt++) {
    bf16x8 avA = {}, avB = {};
    if (lr == 0) {
      avA = *reinterpret_cast<const bf16x8*>(&nhb[kt * 32 + lq * 8]);
      avB = *reinterpret_cast<const bf16x8*>(&nhb[128 + kt * 32 + lq * 8]);
    }
    accY[0] = __builtin_amdgcn_mfma_f32_16x16x32_bf16(avA, w1i[kt], accY[0], 0, 0, 0);
    accY[1] = __builtin_amdgcn_mfma_f32_16x16x32_bf16(avB, w1i[kt], accY[1], 0, 0, 0);
  }
  // reduce accY to the two scalars needed by the epilogue (frees 6 regs)
  const float yiA = __shfl(accY[0][0], lr) + b1v;
  const float yiB = __shfl(accY[1][0], lr) + b1v;

  // ---- WRITE node_j half: Xs[96][128] bf16, 16B-granule XOR swizzle ----
#pragma unroll
  for (int k = 0; k < 3; k++) {
    int r = gr + k * 32;
    uint4 p;
    p.x = pk2(na[k].x, na[k].y); p.y = pk2(na[k].z, na[k].w);
    p.z = pk2(nb[k].x, nb[k].y); p.w = pk2(nb[k].z, nb[k].w);
    *reinterpret_cast<uint4*>(&Xs[r * 128 + ((gw ^ (r & 7)) << 3)]) = p;
  }
  __syncthreads();

  // ---- hoist GEMM1a W frags, THEN issue edge loads (ordered retire!) ----
  bf16x8 w1a[4];
#pragma unroll
  for (int kt = 0; kt < 4; kt++)
    w1a[kt] = *reinterpret_cast<const bf16x8*>(W1e + ((kt * 8 + wave) << 9) + lane * 8);
  float4 ea[3], eb[3];
#pragma unroll
  for (int k = 0; k < 3; k++) {
    int r = gr + k * 32;     // 0..95 (edge rows of the pair are contiguous)
    const float* src = edge_h + ((size_t)n0 * Kn + r) * Cn + gw * 8;
    ea[k] = *reinterpret_cast<const float4*>(src);
    eb[k] = *reinterpret_cast<const float4*>(src + 4);
  }

  // ---- GEMM1a: (96x128 node_j) @ W1[128:256]; edge loads in flight ----
  f32x4 acc[6] = {};
#pragma unroll
  for (int kt = 0; kt < 4; kt++) {
    int sw = (((kt * 4 + lq) ^ (lr & 7)) << 3);
#pragma unroll
    for (int m = 0; m < 6; m++) {
      bf16x8 a = *reinterpret_cast<const bf16x8*>(&Xs[(m * 16 + lr) * 128 + sw]);
      acc[m] = __builtin_amdgcn_mfma_f32_16x16x32_bf16(a, w1a[kt], acc[m], 0, 0, 0);
    }
  }
  __syncthreads();   // Xs node-half reads done before edge overwrite

  // ---- WRITE edge half into the same Xs (loads have landed by now) ----
#pragma unroll
  for (int k = 0; k < 3; k++) {
    int r = gr + k * 32;
    uint4 p;
    p.x = pk2(ea[k].x, ea[k].y); p.y = pk2(ea[k].z, ea[k].w);
    p.z = pk2(eb[k].x, eb[k].y); p.w = pk2(eb[k].z, eb[k].w);
    *reinterpret_cast<uint4*>(&Xs[r * 128 + ((gw ^ (r & 7)) << 3)]) = p;
  }
  __syncthreads();

  // ---- GEMM1b: (96x128 edge) @ W1[256:384] (W frags in-loop, L2-hot) ----
#pragma unroll
  for (int kt = 0; kt < 4; kt++) {
    bf16x8 bf = *reinterpret_cast<const bf16x8*>(W1e + (((kt + 4) * 8 + wave) << 9) + lane * 8);
    int sw = (((kt * 4 + lq) ^ (lr & 7)) << 3);
#pragma unroll
    for (int m = 0; m < 6; m++) {
      bf16x8 a = *reinterpret_cast<const bf16x8*>(&Xs[(m * 16 + lr) * 128 + sw]);
      acc[m] = __builtin_amdgcn_mfma_f32_16x16x32_bf16(a, bf, acc[m], 0, 0, 0);
    }
  }
  __syncthreads();   // Xs edge reads done before H1s (overlay) writes

  // ---- GEMM1 epilogue: +yi +b1, gelu, bf16 -> H1s ----
  {
    int g = colw >> 3, cl = colw & 7;
#pragma unroll
    for (int mt = 0; mt < 6; mt++) {
      float yi = (mt < 3) ? yiA : yiB;
      int r0 = mt * 16 + lq * 4;
      float g0 = gelu_f(acc[mt][0] + yi);
      float g1 = gelu_f(acc[mt][1] + yi);
      float g2 = gelu_f(acc[mt][2] + yi);
      float g3 = gelu_f(acc[mt][3] + yi);
      unsigned p01 = pk2(g0, g1), p23 = pk2(g2, g3);
      H1s[(r0 + 0) * 128 + ((g ^ ((r0 + 0) & 7)) << 3) + cl] = (short)(p01 & 0xffff);
      H1s[(r0 + 1) * 128 + ((g ^ ((r0 + 1) & 7)) << 3) + cl] = (short)(p01 >> 16);
      H1s[(r0 + 2) * 128 + ((g ^ ((r0 + 2) & 7)) << 3) + cl] = (short)(p23 & 0xffff);
      H1s[(r0 + 3) * 128 + ((g ^ ((r0 + 3) & 7)) << 3) + cl] = (short)(p23 >> 16);
    }
  }
  __syncthreads();

  // ---- GEMM2: (96x128) @ W2, fused gelu + column-sum; write hs f32 ----
  f32x4 acc2[6] = {};
#pragma unroll
  for (int kt = 0; kt < 4; kt++) {
    bf16x8 bf = *reinterpret_cast<const bf16x8*>(W2p + ((kt * 8 + wave) << 9) + lane * 8);
    int sw = (((kt * 4 + lq) ^ (lr & 7)) << 3);
#pragma unroll
    for (int m = 0; m < 6; m++) {
      bf16x8 a = *reinterpret_cast<const bf16x8*>(&H1s[(m * 16 + lr) * 128 + sw]);
      acc2[m] = __builtin_amdgcn_mfma_f32_16x16x32_bf16(a, bf, acc2[m], 0, 0, 0);
    }
  }
  {
    float sA = 0.f, sB = 0.f;
#pragma unroll
    for (int mt = 0; mt < 3; mt++)
#pragma unroll
      for (int r = 0; r < 4; r++) {
        sA += gelu_f(acc2[mt][r] + b2v);
        sB += gelu_f(acc2[mt + 3][r] + b2v);
      }
    sA += __shfl_xor(sA, 16);
    sA += __shfl_xor(sA, 32);
    sB += __shfl_xor(sB, 16);
    sB += __shfl_xor(sB, 32);
    if (lq == 0) {
      hs_out[(size_t)n0 * Cn + colw]       = sA;
      hs_out[(size_t)(n0 + 1) * Cn + colw] = sB;
    }
  }
}

// ---------------------------------------------------------------------------
// Kernel 2 (tail, batched): 16 nodes per block.
// msg = (hs @ W3 + 48*b3)/30 ; x = nh + msg ; u = LN(x) ;
// y = nh + u@Wu + bu ; out = LN(y).  Matvecs are dense M=16 MFMA GEMMs.
// Reads hs from the out buffer, overwrites the same rows at the end.
// ---------------------------------------------------------------------------
__global__ __launch_bounds__(256, 4)
void tail_kernel(const float* __restrict__ node_h,
                 const short* __restrict__ wpack,
                 const float* __restrict__ b3,
                 const float* __restrict__ bu,
                 const float* __restrict__ ln_g,
                 const float* __restrict__ ln_b,
                 float* __restrict__ out) {
  // LDS: hsB 16x128 bf16 swz [0,4096) | nhr 16x128 f32 [4096,12288)
  //      xs 16x132 f32 [12288,20736) | usB 16x128 bf16 swz [20736,24832)
  __shared__ __align__(16) char sm2[24832];
  short* hsB = (short*)sm2;
  float* nhr = (float*)(sm2 + 4096);
  float* xs  = (float*)(sm2 + 12288);
  short* usB = (short*)(sm2 + 20736);

  const int tid  = threadIdx.x;
  const int lane = tid & 63;
  const int wave = tid >> 6;
  const int lr   = lane & 15;
  const int lq   = lane >> 4;
  const int n0   = blockIdx.x * G2;

  const short* W3p = wpack + 65536;
  const short* Wup = wpack + 81920;

  // ---- stage node_h (f32) and hs (bf16, swizzled) ----
  {
    int row = tid >> 4, seg = tid & 15;
    const float* p = node_h + (size_t)(n0 + row) * Cn + seg * 8;
    float4 a0 = *reinterpret_cast<const float4*>(p);
    float4 a1 = *reinterpret_cast<const float4*>(p + 4);
    *reinterpret_cast<float4*>(&nhr[row * 128 + seg * 8])     = a0;
    *reinterpret_cast<float4*>(&nhr[row * 128 + seg * 8 + 4]) = a1;
    const float* q = out + (size_t)(n0 + row) * Cn + seg * 8;  // hs scratch
    float4 c0 = *reinterpret_cast<const float4*>(q);
    float4 c1 = *reinterpret_cast<const float4*>(q + 4);
    uint4 pk;
    pk.x = pk2(c0.x, c0.y); pk.y = pk2(c0.z, c0.w);
    pk.z = pk2(c1.x, c1.y); pk.w = pk2(c1.z, c1.w);
    *reinterpret_cast<uint4*>(&hsB[row * 128 + ((seg ^ (row & 7)) << 3)]) = pk;
  }
  __syncthreads();

  // ---- msg GEMM (M=16): hs @ W3 ; x = nh + (.+48*b3)/30 -> xs ----
  f32x4 am[2] = {};
#pragma unroll
  for (int kt = 0; kt < 4; kt++) {
    bf16x8 av = *reinterpret_cast<const bf16x8*>(&hsB[lr * 128 + (((kt * 4 + lq) ^ (lr & 7)) << 3)]);
    bf16x8 bv0 = *reinterpret_cast<const bf16x8*>(W3p + ((kt * 8 + wave * 2 + 0) << 9) + lane * 8);
    bf16x8 bv1 = *reinterpret_cast<const bf16x8*>(W3p + ((kt * 8 + wave * 2 + 1) << 9) + lane * 8);
    am[0] = __builtin_amdgcn_mfma_f32_16x16x32_bf16(av, bv0, am[0], 0, 0, 0);
    am[1] = __builtin_amdgcn_mfma_f32_16x16x32_bf16(av, bv1, am[1], 0, 0, 0);
  }
#pragma unroll
  for (int j = 0; j < 2; j++) {
    int col = (wave * 2 + j) * 16 + lr;
    float bb = 48.0f * b3[col];
#pragma unroll
    for (int r = 0; r < 4; r++) {
      int row = lq * 4 + r;
      xs[row * 132 + col] = nhr[row * 128 + col] + (am[j][r] + bb) * (1.0f / 30.0f);
    }
  }
  __syncthreads();

  // ---- LN1 -> usB (bf16 swz). Wave handles 4 rows; lane owns cols lane,lane+64.
  const float lg1 = ln_g[lane],      lb1v = ln_b[lane];
  const float lg2 = ln_g[lane + 64], lb2v = ln_b[lane + 64];
#pragma unroll
  for (int s = 0; s < 4; s++) {
    int row = wave * 4 + s;
    float v1 = xs[row * 132 + lane];
    float v2 = xs[row * 132 + lane + 64];
    float s1 = v1 + v2, s2 = v1 * v1 + v2 * v2;
#pragma unroll
    for (int off = 32; off >= 1; off >>= 1) {
      s1 += __shfl_xor(s1, off);
      s2 += __shfl_xor(s2, off);
    }
    float mu = s1 * (1.f / 128.f);
    float var = s2 * (1.f / 128.f) - mu * mu;
    float rstd = rsqrtf(var + 1e-5f);
    unsigned u12 = pk2((v1 - mu) * rstd * lg1 + lb1v,
                       (v2 - mu) * rstd * lg2 + lb2v);
    int sw = (row & 7);
    usB[row * 128 + (((lane >> 3) ^ sw) << 3) + (lane & 7)]       = (short)(u12 & 0xffff);
    usB[row * 128 + ((((lane >> 3) + 8) ^ sw) << 3) + (lane & 7)] = (short)(u12 >> 16);
  }
  __syncthreads();

  // ---- upd GEMM (M=16): u @ Wu ; y = nh + . + bu -> xs ----
  f32x4 au[2] = {};
#pragma unroll
  for (int kt = 0; kt < 4; kt++) {
    bf16x8 av = *reinterpret_cast<const bf16x8*>(&usB[lr * 128 + (((kt * 4 + lq) ^ (lr & 7)) << 3)]);
    bf16x8 bv0 = *reinterpret_cast<const bf16x8*>(Wup + ((kt * 8 + wave * 2 + 0) << 9) + lane * 8);
    bf16x8 bv1 = *reinterpret_cast<const bf16x8*>(Wup + ((kt * 8 + wave * 2 + 1) << 9) + lane * 8);
    au[0] = __builtin_amdgcn_mfma_f32_16x16x32_bf16(av, bv0, au[0], 0, 0, 0);
    au[1] = __builtin_amdgcn_mfma_f32_16x16x32_bf16(av, bv1, au[1], 0, 0, 0);
  }
  __syncthreads();   // xs LN1 reads done before overwrite
#pragma unroll
  for (int j = 0; j < 2; j++) {
    int col = (wave * 2 + j) * 16 + lr;
    float bb = bu[col];
#pragma unroll
    for (int r = 0; r < 4; r++) {
      int row = lq * 4 + r;
      xs[row * 132 + col] = nhr[row * 128 + col] + au[j][r] + bb;
    }
  }
  __syncthreads();

  // ---- LN2 -> out ----
#pragma unroll
  for (int s = 0; s < 4; s++) {
    int row = wave * 4 + s;
    float v1 = xs[row * 132 + lane];
    float v2 = xs[row * 132 + lane + 64];
    float s1 = v1 + v2, s2 = v1 * v1 + v2 * v2;
#pragma unroll
    for (int off = 32; off >= 1; off >>= 1) {
      s1 += __shfl_xor(s1, off);
      s2 += __shfl_xor(s2, off);
    }
    float mu = s1 * (1.f / 128.f);
    float var = s2 * (1.f / 128.f) - mu * mu;
    float rstd = rsqrtf(var + 1e-5f);
    out[(size_t)(n0 + row) * Cn + lane]      = (v1 - mu) * rstd * lg1 + lb1v;
    out[(size_t)(n0 + row) * Cn + lane + 64] = (v2 - mu) * rstd * lg2 + lb2v;
  }
}

extern "C" void kernel_launch(void* const* d_in, const int* in_sizes, int n_in,
                              void* d_out, int out_size, void* d_ws, size_t ws_size,
                              hipStream_t stream) {
  const float* node_h     = (const float*)d_in[0];
  const float* edge_h     = (const float*)d_in[1];
  const int*   edge_index = (const int*)  d_in[2];
  const float* W1 = (const float*)d_in[3];
  const float* b1 = (const float*)d_in[4];
  const float* W2 = (const float*)d_in[5];
  const float* b2 = (const float*)d_in[6];
  const float* W3 = (const float*)d_in[7];
  const float* b3 = (const float*)d_in[8];
  const float* Wu = (const float*)d_in[9];
  const float* bu = (const float*)d_in[10];
  const float* ln_g = (const float*)d_in[11];
  const float* ln_b = (const float*)d_in[12];
  float* out   = (float*)d_out;
  short* wpack = (short*)d_ws;   // 192 KiB

  pack_weights<<<48, 256, 0, stream>>>(W1, W2, W3, Wu, wpack);
  node_update_kernel<<<(Bn * Nn) / 2, 512, 0, stream>>>(
      node_h, edge_h, edge_index, wpack, b1, b2, out);
  tail_kernel<<<(Bn * Nn) / G2, 256, 0, stream>>>(
      node_h, wpack, b3, bu, ln_g, ln_b, out);
}

// Round 6
// 198.924 us; speedup vs baseline: 1.4185x; 1.0191x over previous
//
#include <hip/hip_runtime.h>
#include <hip/hip_bf16.h>
#include <math.h>

// Problem constants
#define Bn   2
#define Nn   2048
#define Kn   48
#define Cn   128
#define G2   16     // nodes per block in the tail kernel

typedef short bf16x8 __attribute__((ext_vector_type(8)));
typedef float f32x4  __attribute__((ext_vector_type(4)));

#if __has_builtin(__builtin_amdgcn_cvt_pk_bf16_f32)
#define HAS_PK 1
#endif

__device__ __forceinline__ short f2bf(float f) {
  union { float f; unsigned u; } v; v.f = f;
  unsigned r = v.u + 0x7fffu + ((v.u >> 16) & 1u);
  return (short)(r >> 16);
}

__device__ __forceinline__ unsigned pk2(float a, float b) {
#ifdef HAS_PK
  auto p = __builtin_amdgcn_cvt_pk_bf16_f32(a, b);
  return __builtin_bit_cast(unsigned, p);
#else
  return (unsigned)(unsigned short)f2bf(a) | ((unsigned)(unsigned short)f2bf(b) << 16);
#endif
}

// tanh-GELU with exp2-folded constants; |err| vs erf-gelu ~3e-4.
__device__ __forceinline__ float gelu_f(float x) {
  float z = x * (-2.3021991f - 0.10294200f * x * x);
  float e = __builtin_amdgcn_exp2f(z);
  return x * __builtin_amdgcn_rcpf(1.0f + e);
}

// ---------------------------------------------------------------------------
// Pack weights into bf16 MFMA B-fragment tiles (512 shorts each; lane l holds
// 8 bf16 = W[kt*32 + (l>>4)*8 + j][nt*16 + (l&15)]).
// ws (shorts): W1i [0,16384) | W1e [16384,49152) | W2 [49152,65536)
//              W3 [65536,81920) | Wu [81920,98304)
// ---------------------------------------------------------------------------
__global__ void pack_weights(const float* __restrict__ W1,
                             const float* __restrict__ W2,
                             const float* __restrict__ W3,
                             const float* __restrict__ Wu,
                             short* __restrict__ ws) {
  int tid = blockIdx.x * blockDim.x + threadIdx.x;
  if (tid >= 192 * 64) return;
  int lane = tid & 63;
  int tile = tid >> 6;
  const float* W; short* dst;
  if (tile < 32)       { W = W1;         dst = ws; }
  else if (tile < 96)  { W = W1 + 16384; dst = ws + 16384; tile -= 32; }
  else if (tile < 128) { W = W2;         dst = ws + 49152; tile -= 96; }
  else if (tile < 160) { W = W3;         dst = ws + 65536; tile -= 128; }
  else                 { W = Wu;         dst = ws + 81920; tile -= 160; }
  int kt = tile >> 3, nt = tile & 7;
  int n  = nt * 16 + (lane & 15);
  int k0 = kt * 32 + (lane >> 4) * 8;
  union { short s[8]; bf16x8 v; } u8;
#pragma unroll
  for (int j = 0; j < 8; j++) u8.s[j] = f2bf(W[(k0 + j) * 128 + n]);
  *reinterpret_cast<bf16x8*>(dst + (tile << 9) + lane * 8) = u8.v;
}

// ---------------------------------------------------------------------------
// Kernel 1: edge MLP, TWO nodes per block. 512 thr = 8 waves; wave w owns
// output cols [w*16, w*16+16). M = 96 rows (48 edges x 2 nodes). K-split
// GEMM1 (node_j half, then edge half in the same 24.5KB LDS buffer).
// Round-6 change: complete the T14 schedule. r5's VGPR_Count=40 proved the
// compiler sank the issue-early edge loads (24 regs can't be in flight in a
// 40-reg kernel). Fix: (a) __launch_bounds__(512,4) -> 128-reg cap,
// 2 blocks/CU (r2-vs-r4 showed waves/CU 24<->32 neutral; ILP is the lever);
// (b) sched_barrier(0) pins after each load-issue block so LLVM cannot sink
// them; (c) GEMM1b's W fragments hoisted with GEMM1a's, AHEAD of the edge
// loads (in-order vmcnt retire keeps W waits off the edge stream). Peak
// live ~95 VGPR < 128, no spill (r3's bomb was a ~60-reg deficit).
// ---------------------------------------------------------------------------
__global__ __launch_bounds__(512, 4)
void node_update_kernel(const float* __restrict__ node_h,
                        const float* __restrict__ edge_h,
                        const int*   __restrict__ edge_index,
                        const short* __restrict__ wpack,
                        const float* __restrict__ b1,
                        const float* __restrict__ b2,
                        float* __restrict__ hs_out) {
  // LDS (bytes), 25472 total:
  //  [0,24576)      Xs 96x128 bf16 swizzled (node_j half, then edge half,
  //                 then H1s overlays the same extents)
  //  [24576,25088)  nhb: node_i bf16 x256 (2 nodes)
  //  [25088,25472)  idx_s x96
  __shared__ __align__(16) char smem[25472];
  short* Xs    = (short*)smem;
  short* H1s   = (short*)smem;           // full overlay of Xs
  short* nhb   = (short*)(smem + 24576);
  int*   idx_s = (int*)  (smem + 25088);

  const int tid  = threadIdx.x;
  const int n0   = blockIdx.x * 2;     // first node of the pair
  const int bb   = n0 >> 11;           // batch (pair never straddles: 2048 even)
  const int lane = tid & 63;
  const int wave = tid >> 6;           // 0..7
  const int lr   = lane & 15;
  const int lq   = lane >> 4;

  const short* W1i = wpack;
  const short* W1e = wpack + 16384;
  const short* W2p = wpack + 49152;

  // ---- hoist W1i fragments + biases (issued before any data gather) ----
  bf16x8 w1i[4];
#pragma unroll
  for (int kt = 0; kt < 4; kt++)
    w1i[kt] = *reinterpret_cast<const bf16x8*>(W1i + ((kt * 8 + wave) << 9) + lane * 8);
  const int colw = wave * 16 + lr;
  const float b1v = b1[colw];
  const float b2v = b2[colw];

  // ---- phase 0: node_i bf16 (2 nodes) + neighbor indices (96) ----
  if (tid < 256) {
    nhb[tid] = f2bf(node_h[(size_t)n0 * Cn + tid]);
  } else if (tid < 352) {
    idx_s[tid - 256] = edge_index[n0 * Kn + (tid - 256)];
  }
  __syncthreads();

  const int gw = tid & 15;   // granule within row
  const int gr = tid >> 4;   // 0..31

  // ---- ISSUE node_j gather into registers (latency hidden under accY) ----
  float4 na[3], nb[3];
#pragma unroll
  for (int k = 0; k < 3; k++) {
    int r = gr + k * 32;     // 0..95
    const float* src = node_h + (size_t)(bb * Nn + idx_s[r]) * Cn + gw * 8;
    na[k] = *reinterpret_cast<const float4*>(src);
    nb[k] = *reinterpret_cast<const float4*>(src + 4);
  }
  __builtin_amdgcn_sched_barrier(0);   // pin: loads issued HERE, not sunk

  // ---- node_i row-vector MFMAs for both nodes (W1i already in regs) ----
  f32x4 accY[2] = {};   // [node]
#pragma unroll
  for (int kt = 0; kt < 4; kt++) {
    bf16x8 avA = {}, avB = {};
    if (lr == 0) {
      avA = *reinterpret_cast<const bf16x8*>(&nhb[kt * 32 + lq * 8]);
      avB = *reinterpret_cast<const bf16x8*>(&nhb[128 + kt * 32 + lq * 8]);
    }
    accY[0] = __builtin_amdgcn_mfma_f32_16x16x32_bf16(avA, w1i[kt], accY[0], 0, 0, 0);
    accY[1] = __builtin_amdgcn_mfma_f32_16x16x32_bf16(avB, w1i[kt], accY[1], 0, 0, 0);
  }
  // reduce accY to the two scalars needed by the epilogue (frees 6 regs)
  const float yiA = __shfl(accY[0][0], lr) + b1v;
  const float yiB = __shfl(accY[1][0], lr) + b1v;

  // ---- WRITE node_j half: Xs[96][128] bf16, 16B-granule XOR swizzle ----
#pragma unroll
  for (int k = 0; k < 3; k++) {
    int r = gr + k * 32;
    uint4 p;
    p.x = pk2(na[k].x, na[k].y); p.y = pk2(na[k].z, na[k].w);
    p.z = pk2(nb[k].x, nb[k].y); p.w = pk2(nb[k].z, nb[k].w);
    *reinterpret_cast<uint4*>(&Xs[r * 128 + ((gw ^ (r & 7)) << 3)]) = p;
  }
  __syncthreads();

  // ---- hoist GEMM1a+1b W frags, THEN issue edge loads (ordered retire!) ----
  bf16x8 w1a[4], w1b[4];
#pragma unroll
  for (int kt = 0; kt < 4; kt++)
    w1a[kt] = *reinterpret_cast<const bf16x8*>(W1e + ((kt * 8 + wave) << 9) + lane * 8);
#pragma unroll
  for (int kt = 0; kt < 4; kt++)
    w1b[kt] = *reinterpret_cast<const bf16x8*>(W1e + (((kt + 4) * 8 + wave) << 9) + lane * 8);
  float4 ea[3], eb[3];
#pragma unroll
  for (int k = 0; k < 3; k++) {
    int r = gr + k * 32;     // 0..95 (edge rows of the pair are contiguous)
    const float* src = edge_h + ((size_t)n0 * Kn + r) * Cn + gw * 8;
    ea[k] = *reinterpret_cast<const float4*>(src);
    eb[k] = *reinterpret_cast<const float4*>(src + 4);
  }
  __builtin_amdgcn_sched_barrier(0);   // pin: edge loads stay in flight here

  // ---- GEMM1a: (96x128 node_j) @ W1[128:256]; edge loads in flight ----
  f32x4 acc[6] = {};
#pragma unroll
  for (int kt = 0; kt < 4; kt++) {
    int sw = (((kt * 4 + lq) ^ (lr & 7)) << 3);
#pragma unroll
    for (int m = 0; m < 6; m++) {
      bf16x8 a = *reinterpret_cast<const bf16x8*>(&Xs[(m * 16 + lr) * 128 + sw]);
      acc[m] = __builtin_amdgcn_mfma_f32_16x16x32_bf16(a, w1a[kt], acc[m], 0, 0, 0);
    }
  }
  __syncthreads();   // Xs node-half reads done before edge overwrite

  // ---- WRITE edge half into the same Xs (loads have landed by now) ----
#pragma unroll
  for (int k = 0; k < 3; k++) {
    int r = gr + k * 32;
    uint4 p;
    p.x = pk2(ea[k].x, ea[k].y); p.y = pk2(ea[k].z, ea[k].w);
    p.z = pk2(eb[k].x, eb[k].y); p.w = pk2(eb[k].z, eb[k].w);
    *reinterpret_cast<uint4*>(&Xs[r * 128 + ((gw ^ (r & 7)) << 3)]) = p;
  }
  __syncthreads();

  // ---- GEMM1b: (96x128 edge) @ W1[256:384] (W frags already in regs) ----
#pragma unroll
  for (int kt = 0; kt < 4; kt++) {
    int sw = (((kt * 4 + lq) ^ (lr & 7)) << 3);
#pragma unroll
    for (int m = 0; m < 6; m++) {
      bf16x8 a = *reinterpret_cast<const bf16x8*>(&Xs[(m * 16 + lr) * 128 + sw]);
      acc[m] = __builtin_amdgcn_mfma_f32_16x16x32_bf16(a, w1b[kt], acc[m], 0, 0, 0);
    }
  }
  __syncthreads();   // Xs edge reads done before H1s (overlay) writes

  // ---- GEMM1 epilogue: +yi +b1, gelu, bf16 -> H1s ----
  {
    int g = colw >> 3, cl = colw & 7;
#pragma unroll
    for (int mt = 0; mt < 6; mt++) {
      float yi = (mt < 3) ? yiA : yiB;
      int r0 = mt * 16 + lq * 4;
      float g0 = gelu_f(acc[mt][0] + yi);
      float g1 = gelu_f(acc[mt][1] + yi);
      float g2 = gelu_f(acc[mt][2] + yi);
      float g3 = gelu_f(acc[mt][3] + yi);
      unsigned p01 = pk2(g0, g1), p23 = pk2(g2, g3);
      H1s[(r0 + 0) * 128 + ((g ^ ((r0 + 0) & 7)) << 3) + cl] = (short)(p01 & 0xffff);
      H1s[(r0 + 1) * 128 + ((g ^ ((r0 + 1) & 7)) << 3) + cl] = (short)(p01 >> 16);
      H1s[(r0 + 2) * 128 + ((g ^ ((r0 + 2) & 7)) << 3) + cl] = (short)(p23 & 0xffff);
      H1s[(r0 + 3) * 128 + ((g ^ ((r0 + 3) & 7)) << 3) + cl] = (short)(p23 >> 16);
    }
  }
  __syncthreads();

  // ---- GEMM2: (96x128) @ W2, fused gelu + column-sum; write hs f32 ----
  f32x4 acc2[6] = {};
#pragma unroll
  for (int kt = 0; kt < 4; kt++) {
    bf16x8 bf = *reinterpret_cast<const bf16x8*>(W2p + ((kt * 8 + wave) << 9) + lane * 8);
    int sw = (((kt * 4 + lq) ^ (lr & 7)) << 3);
#pragma unroll
    for (int m = 0; m < 6; m++) {
      bf16x8 a = *reinterpret_cast<const bf16x8*>(&H1s[(m * 16 + lr) * 128 + sw]);
      acc2[m] = __builtin_amdgcn_mfma_f32_16x16x32_bf16(a, bf, acc2[m], 0, 0, 0);
    }
  }
  {
    float sA = 0.f, sB = 0.f;
#pragma unroll
    for (int mt = 0; mt < 3; mt++)
#pragma unroll
      for (int r = 0; r < 4; r++) {
        sA += gelu_f(acc2[mt][r] + b2v);
        sB += gelu_f(acc2[mt + 3][r] + b2v);
      }
    sA += __shfl_xor(sA, 16);
    sA += __shfl_xor(sA, 32);
    sB += __shfl_xor(sB, 16);
    sB += __shfl_xor(sB, 32);
    if (lq == 0) {
      hs_out[(size_t)n0 * Cn + colw]       = sA;
      hs_out[(size_t)(n0 + 1) * Cn + colw] = sB;
    }
  }
}

// ---------------------------------------------------------------------------
// Kernel 2 (tail, batched): 16 nodes per block.
// msg = (hs @ W3 + 48*b3)/30 ; x = nh + msg ; u = LN(x) ;
// y = nh + u@Wu + bu ; out = LN(y).  Matvecs are dense M=16 MFMA GEMMs.
// Reads hs from the out buffer, overwrites the same rows at the end.
// ---------------------------------------------------------------------------
__global__ __launch_bounds__(256, 4)
void tail_kernel(const float* __restrict__ node_h,
                 const short* __restrict__ wpack,
                 const float* __restrict__ b3,
                 const float* __restrict__ bu,
                 const float* __restrict__ ln_g,
                 const float* __restrict__ ln_b,
                 float* __restrict__ out) {
  // LDS: hsB 16x128 bf16 swz [0,4096) | nhr 16x128 f32 [4096,12288)
  //      xs 16x132 f32 [12288,20736) | usB 16x128 bf16 swz [20736,24832)
  __shared__ __align__(16) char sm2[24832];
  short* hsB = (short*)sm2;
  float* nhr = (float*)(sm2 + 4096);
  float* xs  = (float*)(sm2 + 12288);
  short* usB = (short*)(sm2 + 20736);

  const int tid  = threadIdx.x;
  const int lane = tid & 63;
  const int wave = tid >> 6;
  const int lr   = lane & 15;
  const int lq   = lane >> 4;
  const int n0   = blockIdx.x * G2;

  const short* W3p = wpack + 65536;
  const short* Wup = wpack + 81920;

  // ---- stage node_h (f32) and hs (bf16, swizzled) ----
  {
    int row = tid >> 4, seg = tid & 15;
    const float* p = node_h + (size_t)(n0 + row) * Cn + seg * 8;
    float4 a0 = *reinterpret_cast<const float4*>(p);
    float4 a1 = *reinterpret_cast<const float4*>(p + 4);
    *reinterpret_cast<float4*>(&nhr[row * 128 + seg * 8])     = a0;
    *reinterpret_cast<float4*>(&nhr[row * 128 + seg * 8 + 4]) = a1;
    const float* q = out + (size_t)(n0 + row) * Cn + seg * 8;  // hs scratch
    float4 c0 = *reinterpret_cast<const float4*>(q);
    float4 c1 = *reinterpret_cast<const float4*>(q + 4);
    uint4 pk;
    pk.x = pk2(c0.x, c0.y); pk.y = pk2(c0.z, c0.w);
    pk.z = pk2(c1.x, c1.y); pk.w = pk2(c1.z, c1.w);
    *reinterpret_cast<uint4*>(&hsB[row * 128 + ((seg ^ (row & 7)) << 3)]) = pk;
  }
  __syncthreads();

  // ---- msg GEMM (M=16): hs @ W3 ; x = nh + (.+48*b3)/30 -> xs ----
  f32x4 am[2] = {};
#pragma unroll
  for (int kt = 0; kt < 4; kt++) {
    bf16x8 av = *reinterpret_cast<const bf16x8*>(&hsB[lr * 128 + (((kt * 4 + lq) ^ (lr & 7)) << 3)]);
    bf16x8 bv0 = *reinterpret_cast<const bf16x8*>(W3p + ((kt * 8 + wave * 2 + 0) << 9) + lane * 8);
    bf16x8 bv1 = *reinterpret_cast<const bf16x8*>(W3p + ((kt * 8 + wave * 2 + 1) << 9) + lane * 8);
    am[0] = __builtin_amdgcn_mfma_f32_16x16x32_bf16(av, bv0, am[0], 0, 0, 0);
    am[1] = __builtin_amdgcn_mfma_f32_16x16x32_bf16(av, bv1, am[1], 0, 0, 0);
  }
#pragma unroll
  for (int j = 0; j < 2; j++) {
    int col = (wave * 2 + j) * 16 + lr;
    float bb = 48.0f * b3[col];
#pragma unroll
    for (int r = 0; r < 4; r++) {
      int row = lq * 4 + r;
      xs[row * 132 + col] = nhr[row * 128 + col] + (am[j][r] + bb) * (1.0f / 30.0f);
    }
  }
  __syncthreads();

  // ---- LN1 -> usB (bf16 swz). Wave handles 4 rows; lane owns cols lane,lane+64.
  const float lg1 = ln_g[lane],      lb1v = ln_b[lane];
  const float lg2 = ln_g[lane + 64], lb2v = ln_b[lane + 64];
#pragma unroll
  for (int s = 0; s < 4; s++) {
    int row = wave * 4 + s;
    float v1 = xs[row * 132 + lane];
    float v2 = xs[row * 132 + lane + 64];
    float s1 = v1 + v2, s2 = v1 * v1 + v2 * v2;
#pragma unroll
    for (int off = 32; off >= 1; off >>= 1) {
      s1 += __shfl_xor(s1, off);
      s2 += __shfl_xor(s2, off);
    }
    float mu = s1 * (1.f / 128.f);
    float var = s2 * (1.f / 128.f) - mu * mu;
    float rstd = rsqrtf(var + 1e-5f);
    unsigned u12 = pk2((v1 - mu) * rstd * lg1 + lb1v,
                       (v2 - mu) * rstd * lg2 + lb2v);
    int sw = (row & 7);
    usB[row * 128 + (((lane >> 3) ^ sw) << 3) + (lane & 7)]       = (short)(u12 & 0xffff);
    usB[row * 128 + ((((lane >> 3) + 8) ^ sw) << 3) + (lane & 7)] = (short)(u12 >> 16);
  }
  __syncthreads();

  // ---- upd GEMM (M=16): u @ Wu ; y = nh + . + bu -> xs ----
  f32x4 au[2] = {};
#pragma unroll
  for (int kt = 0; kt < 4; kt++) {
    bf16x8 av = *reinterpret_cast<const bf16x8*>(&usB[lr * 128 + (((kt * 4 + lq) ^ (lr & 7)) << 3)]);
    bf16x8 bv0 = *reinterpret_cast<const bf16x8*>(Wup + ((kt * 8 + wave * 2 + 0) << 9) + lane * 8);
    bf16x8 bv1 = *reinterpret_cast<const bf16x8*>(Wup + ((kt * 8 + wave * 2 + 1) << 9) + lane * 8);
    au[0] = __builtin_amdgcn_mfma_f32_16x16x32_bf16(av, bv0, au[0], 0, 0, 0);
    au[1] = __builtin_amdgcn_mfma_f32_16x16x32_bf16(av, bv1, au[1], 0, 0, 0);
  }
  __syncthreads();   // xs LN1 reads done before overwrite
#pragma unroll
  for (int j = 0; j < 2; j++) {
    int col = (wave * 2 + j) * 16 + lr;
    float bb = bu[col];
#pragma unroll
    for (int r = 0; r < 4; r++) {
      int row = lq * 4 + r;
      xs[row * 132 + col] = nhr[row * 128 + col] + au[j][r] + bb;
    }
  }
  __syncthreads();

  // ---- LN2 -> out ----
#pragma unroll
  for (int s = 0; s < 4; s++) {
    int row = wave * 4 + s;
    float v1 = xs[row * 132 + lane];
    float v2 = xs[row * 132 + lane + 64];
    float s1 = v1 + v2, s2 = v1 * v1 + v2 * v2;
#pragma unroll
    for (int off = 32; off >= 1; off >>= 1) {
      s1 += __shfl_xor(s1, off);
      s2 += __shfl_xor(s2, off);
    }
    float mu = s1 * (1.f / 128.f);
    float var = s2 * (1.f / 128.f) - mu * mu;
    float rstd = rsqrtf(var + 1e-5f);
    out[(size_t)(n0 + row) * Cn + lane]      = (v1 - mu) * rstd * lg1 + lb1v;
    out[(size_t)(n0 + row) * Cn + lane + 64] = (v2 - mu) * rstd * lg2 + lb2v;
  }
}

extern "C" void kernel_launch(void* const* d_in, const int* in_sizes, int n_in,
                              void* d_out, int out_size, void* d_ws, size_t ws_size,
                              hipStream_t stream) {
  const float* node_h     = (const float*)d_in[0];
  const float* edge_h     = (const float*)d_in[1];
  const int*   edge_index = (const int*)  d_in[2];
  const float* W1 = (const float*)d_in[3];
  const float* b1 = (const float*)d_in[4];
  const float* W2 = (const float*)d_in[5];
  const float* b2 = (const float*)d_in[6];
  const float* W3 = (const float*)d_in[7];
  const float* b3 = (const float*)d_in[8];
  const float* Wu = (const float*)d_in[9];
  const float* bu = (const float*)d_in[10];
  const float* ln_g = (const float*)d_in[11];
  const float* ln_b = (const float*)d_in[12];
  float* out   = (float*)d_out;
  short* wpack = (short*)d_ws;   // 192 KiB

  pack_weights<<<48, 256, 0, stream>>>(W1, W2, W3, Wu, wpack);
  node_update_kernel<<<(Bn * Nn) / 2, 512, 0, stream>>>(
      node_h, edge_h, edge_index, wpack, b1, b2, out);
  tail_kernel<<<(Bn * Nn) / G2, 256, 0, stream>>>(
      node_h, wpack, b3, bu, ln_g, ln_b, out);
}